// Round 2
// baseline (458.125 us; speedup 1.0000x reference)
//
#include <hip/hip_runtime.h>
#include <math.h>

#define LRELU(v) ((v) > 0.f ? (v) : 0.2f * (v))

__device__ __forceinline__ float wsum(float v) {
#pragma unroll
    for (int m = 1; m < 64; m <<= 1) v += __shfl_xor(v, m);
    return v;
}
__device__ __forceinline__ float wmax(float v) {
#pragma unroll
    for (int m = 1; m < 64; m <<= 1) v = fmaxf(v, __shfl_xor(v, m));
    return v;
}

// consts layout (floats):
// [0]=cs1 [1]=cd1 [2..65]=va_s(64) [66..129]=va_d(64) [130..257]=bc(128)
// [258..8449]=WcT (64 x 128): WcT[k*128+c] = sum_j Wl2[c][j]*W2[j][k]
#define C_VAS 2
#define C_VAD 66
#define C_BC 130
#define C_WCT 258

__global__ void k0_precompute(const float* W1, const float* as1, const float* ad1,
                              const float* W2, const float* as2, const float* ad2,
                              const float* b2, const float* Wl2, const float* bl2,
                              float* consts) {
    int b = blockIdx.x, t = threadIdx.x;  // blockDim = 128
    if (b < 64) {
        float acc = 0.f;
#pragma unroll 8
        for (int j = 0; j < 128; ++j) acc += Wl2[t * 128 + j] * W2[j * 64 + b];
        consts[C_WCT + b * 128 + t] = acc;
    } else {
        if (t < 64) {
            float vs = 0.f, vd = 0.f;
            for (int c = 0; c < 128; ++c) {
                float w = W2[c * 64 + t];
                vs += as2[c] * w;
                vd += ad2[c] * w;
            }
            consts[C_VAS + t] = vs;
            consts[C_VAD + t] = vd;
        }
        float acc = bl2[t];
        for (int j = 0; j < 128; ++j) acc += Wl2[t * 128 + j] * b2[j];
        consts[C_BC + t] = acc;
        if (t < 64) {
            float p = W1[t] * as1[t], q = W1[t] * ad1[t];
#pragma unroll
            for (int m = 1; m < 64; m <<= 1) { p += __shfl_xor(p, m); q += __shfl_xor(q, m); }
            if (t == 0) { consts[0] = p; consts[1] = q; }
        }
    }
}

__global__ void kz_zero(int* deg, int N) {
    int i = blockIdx.x * blockDim.x + threadIdx.x;
    if (i < N) deg[i] = 0;
}

__global__ void k_deg(const int* dst, int* deg, int E) {
    int e = blockIdx.x * blockDim.x + threadIdx.x;
    if (e < E) atomicAdd(&deg[dst[e]], 1);
}

__global__ void k_scan(const int* deg, int* off, int* cur, int N) {
    __shared__ int sm[1024];
    int t = threadIdx.x;
    int chunk = (N + 1023) >> 10;
    int lo = t * chunk;
    int hi = lo + chunk;
    if (lo > N) lo = N;
    if (hi > N) hi = N;
    int s = 0;
    for (int i = lo; i < hi; ++i) s += deg[i];
    sm[t] = s;
    __syncthreads();
    for (int d = 1; d < 1024; d <<= 1) {
        int v = (t >= d) ? sm[t - d] : 0;
        __syncthreads();
        sm[t] += v;
        __syncthreads();
    }
    int pre = (t == 0) ? 0 : sm[t - 1];
    for (int i = lo; i < hi; ++i) {
        off[i] = pre;
        cur[i] = pre;
        pre += deg[i];
    }
    if (t == 1023) off[N] = sm[1023];
}

__global__ void k_scatter(const int* src, const int* dst, int* cur, int* csr_src, int E) {
    int e = blockIdx.x * blockDim.x + threadIdx.x;
    if (e >= E) return;
    int d = dst[e];
    int pos = atomicAdd(&cur[d], 1);
    csr_src[pos] = src[e];
}

// Layer 1 (scalar GAT) + hrelu/a2s/a2d production. One 64-lane wave per node.
__global__ void kL1_fused(const float* x, const float* consts, const int* off,
                          const int* csr_src, const float* W1, const float* b1,
                          float* hrelu, float* a2s, float* a2d, int N) {
    int i = blockIdx.x * blockDim.y + threadIdx.y;
    int lane = threadIdx.x;
    if (i >= N) return;
    float cs = consts[0], cd = consts[1];
    float xi = x[i];
    float m = LRELU(xi * (cs + cd));  // self-loop score
    float z = 1.f, wx = xi;           // self-loop weight 1 at m
    int lo = off[i], hi = off[i + 1];
    for (int base = lo; base < hi; base += 64) {
        int j = base + lane;
        float e = -INFINITY, xs = 0.f;
        if (j < hi) {
            int s = csr_src[j];
            xs = x[s];
            e = LRELU(cs * xs + cd * xi);
        }
        float mn = fmaxf(m, wmax(e));
        float sc = __expf(m - mn);
        float w = (j < hi) ? __expf(e - mn) : 0.f;
        z = z * sc + wsum(w);
        wx = wx * sc + wsum(w * xs);
        m = mn;
    }
    float a1 = wx / z;
    float h = fmaxf(a1 * W1[lane] + b1[lane], 0.f);
    hrelu[(size_t)i * 64 + lane] = h;
    float ps = wsum(h * consts[C_VAS + lane]);
    float pd = wsum(h * consts[C_VAD + lane]);
    if (lane == 0) { a2s[i] = ps; a2d[i] = pd; }
}

// Layer 2 GAT agg (vector, online softmax) + fused Wc matmul + final output.
__global__ void kL2_fused(const float* x, const float* consts, const int* off,
                          const int* csr_src, const float* a2s, const float* a2d,
                          const float* hrelu, const float* Wl1, const float* bl1,
                          float* out, int N) {
    int i = blockIdx.x * blockDim.y + threadIdx.y;
    int lane = threadIdx.x;
    if (i >= N) return;
    float adi = a2d[i];
    float m = LRELU(a2s[i] + adi);              // self-loop score
    float z = 1.f;
    float acc = hrelu[(size_t)i * 64 + lane];   // self-loop contribution (w=1)
    int lo = off[i], hi = off[i + 1];
    for (int base = lo; base < hi; base += 64) {
        int j = base + lane;
        float e = -INFINITY;
        int s = 0;
        if (j < hi) {
            s = csr_src[j];
            e = LRELU(a2s[s] + adi);
        }
        float mn = fmaxf(m, wmax(e));
        float sc = __expf(m - mn);
        float we = (j < hi) ? __expf(e - mn) : 0.f;
        z = z * sc + wsum(we);
        acc *= sc;
        int cnt = min(64, hi - base);
        for (int l = 0; l < cnt; ++l) {
            float w = __shfl(we, l);
            int sl = __shfl(s, l);
            acc += w * hrelu[(size_t)sl * 64 + lane];
        }
        m = mn;
    }
    float v = acc / z;
    float acc1 = consts[C_BC + lane], acc2 = consts[C_BC + 64 + lane];
#pragma unroll 8
    for (int j = 0; j < 64; ++j) {
        float vj = __shfl(v, j);
        acc1 += consts[C_WCT + j * 128 + lane] * vj;
        acc2 += consts[C_WCT + j * 128 + 64 + lane] * vj;
    }
    float xi = x[i];
    out[(size_t)i * 128 + lane]      = xi * Wl1[lane]      + bl1[lane]      + fmaxf(acc1, 0.f);
    out[(size_t)i * 128 + 64 + lane] = xi * Wl1[64 + lane] + bl1[64 + lane] + fmaxf(acc2, 0.f);
}

extern "C" void kernel_launch(void* const* d_in, const int* in_sizes, int n_in,
                              void* d_out, int out_size, void* d_ws, size_t ws_size,
                              hipStream_t stream) {
    const float* x   = (const float*)d_in[0];
    const int*   ei  = (const int*)d_in[1];
    const float* W1  = (const float*)d_in[2];
    const float* as1 = (const float*)d_in[3];
    const float* ad1 = (const float*)d_in[4];
    const float* b1  = (const float*)d_in[5];
    const float* W2  = (const float*)d_in[6];
    const float* as2 = (const float*)d_in[7];
    const float* ad2 = (const float*)d_in[8];
    const float* b2  = (const float*)d_in[9];
    const float* Wl1 = (const float*)d_in[10];
    const float* bl1 = (const float*)d_in[11];
    const float* Wl2 = (const float*)d_in[12];
    const float* bl2 = (const float*)d_in[13];

    int N = in_sizes[0];
    int E = in_sizes[1] / 2;
    const int* srcp = ei;
    const int* dstp = ei + E;

    float* ws = (float*)d_ws;
    float* consts = ws;                         // 8704 floats
    int*   deg    = (int*)(ws + 8704);          // N
    int*   off    = deg + N;                    // N+1
    int*   cur    = off + N + 1;                // N
    int*   csr    = cur + N;                    // E
    float* a2s    = (float*)(csr + E);          // N
    float* a2d    = a2s + N;                    // N
    float* hrel   = a2d + N;                    // 64*N

    dim3 b256(256);
    dim3 bw(64, 4);

    k0_precompute<<<65, 128, 0, stream>>>(W1, as1, ad1, W2, as2, ad2, b2, Wl2, bl2, consts);
    kz_zero<<<(N + 255) / 256, b256, 0, stream>>>(deg, N);
    k_deg<<<(E + 255) / 256, b256, 0, stream>>>(dstp, deg, E);
    k_scan<<<1, 1024, 0, stream>>>(deg, off, cur, N);
    k_scatter<<<(E + 255) / 256, b256, 0, stream>>>(srcp, dstp, cur, csr, E);
    kL1_fused<<<(N + 3) / 4, bw, 0, stream>>>(x, consts, off, csr, W1, b1, hrel, a2s, a2d, N);
    kL2_fused<<<(N + 3) / 4, bw, 0, stream>>>(x, consts, off, csr, a2s, a2d, hrel, Wl1, bl1,
                                              (float*)d_out, N);
}

// Round 3
// 245.531 us; speedup vs baseline: 1.8659x; 1.8659x over previous
//
#include <hip/hip_runtime.h>
#include <math.h>

#define LRELU(v) ((v) > 0.f ? (v) : 0.2f * (v))

__device__ __forceinline__ float wsum(float v) {
#pragma unroll
    for (int m = 1; m < 64; m <<= 1) v += __shfl_xor(v, m);
    return v;
}
__device__ __forceinline__ float wmax(float v) {
#pragma unroll
    for (int m = 1; m < 64; m <<= 1) v = fmaxf(v, __shfl_xor(v, m));
    return v;
}
__device__ __forceinline__ int wsumi(int v) {
#pragma unroll
    for (int m = 1; m < 64; m <<= 1) v += __shfl_xor(v, m);
    return v;
}

// consts layout (floats):
// [0]=cs1 [1]=cd1 [2..65]=va_s(64) [66..129]=va_d(64) [130..257]=bc(128)
// [258..8449]=WcT (64 x 128): WcT[k*128+c] = sum_j Wl2[c][j]*W2[j][k]
#define C_VAS 2
#define C_VAD 66
#define C_BC 130
#define C_WCT 258

__global__ void k0_precompute(const float* W1, const float* as1, const float* ad1,
                              const float* W2, const float* as2, const float* ad2,
                              const float* b2, const float* Wl2, const float* bl2,
                              float* consts) {
    int b = blockIdx.x, t = threadIdx.x;  // blockDim = 128
    if (b < 64) {
        float acc = 0.f;
#pragma unroll 8
        for (int j = 0; j < 128; ++j) acc += Wl2[t * 128 + j] * W2[j * 64 + b];
        consts[C_WCT + b * 128 + t] = acc;
    } else {
        if (t < 64) {
            float vs = 0.f, vd = 0.f;
            for (int c = 0; c < 128; ++c) {
                float w = W2[c * 64 + t];
                vs += as2[c] * w;
                vd += ad2[c] * w;
            }
            consts[C_VAS + t] = vs;
            consts[C_VAD + t] = vd;
        }
        float acc = bl2[t];
        for (int j = 0; j < 128; ++j) acc += Wl2[t * 128 + j] * b2[j];
        consts[C_BC + t] = acc;
        if (t < 64) {
            float p = W1[t] * as1[t], q = W1[t] * ad1[t];
#pragma unroll
            for (int m = 1; m < 64; m <<= 1) { p += __shfl_xor(p, m); q += __shfl_xor(q, m); }
            if (t == 0) { consts[0] = p; consts[1] = q; }
        }
    }
}

__global__ void kz_zero(int* deg, int N) {
    int i = blockIdx.x * blockDim.x + threadIdx.x;
    if (i < N) deg[i] = 0;
}

__global__ void k_deg(const int* dst, int* deg, int E) {
    int e = blockIdx.x * blockDim.x + threadIdx.x;
    if (e < E) atomicAdd(&deg[dst[e]], 1);
}

// ---- hierarchical scan: 2048 elems per block ----
__global__ void k_bsum(const int* deg, int* bsum, int N) {
    __shared__ int ws[4];
    int t = threadIdx.x, lane = t & 63, wy = t >> 6;
    int base = blockIdx.x * 2048 + t * 8;
    int s = 0;
#pragma unroll
    for (int k = 0; k < 8; ++k) {
        int idx = base + k;
        if (idx < N) s += deg[idx];
    }
    s = wsumi(s);
    if (lane == 0) ws[wy] = s;
    __syncthreads();
    if (t == 0) bsum[blockIdx.x] = ws[0] + ws[1] + ws[2] + ws[3];
}

__global__ void k_bscan(const int* bsum, int* bbase, int NB) {
    __shared__ int sm[256];
    int t = threadIdx.x;  // 256; assumes NB <= 256
    int v = (t < NB) ? bsum[t] : 0;
    sm[t] = v;
    __syncthreads();
    for (int d = 1; d < 256; d <<= 1) {
        int u = (t >= d) ? sm[t - d] : 0;
        __syncthreads();
        sm[t] += u;
        __syncthreads();
    }
    if (t < NB) bbase[t] = sm[t] - v;  // exclusive
}

__global__ void k_scan2(const int* deg, const int* bbase, int* off, int* cur, int N, int NB) {
    __shared__ int wsms[4];
    int b = blockIdx.x, t = threadIdx.x;  // 256 threads
    int lane = t & 63, wy = t >> 6;
    int base = b * 2048 + t * 8;
    int v[8];
    int s = 0;
#pragma unroll
    for (int k = 0; k < 8; ++k) {
        int idx = base + k;
        v[k] = (idx < N) ? deg[idx] : 0;
        s += v[k];
    }
    int sc = s;  // wave inclusive scan of per-thread sums
#pragma unroll
    for (int d = 1; d < 64; d <<= 1) {
        int u = __shfl_up(sc, d);
        if (lane >= d) sc += u;
    }
    if (lane == 63) wsms[wy] = sc;
    __syncthreads();
    int wbase = 0;
    for (int w = 0; w < wy; ++w) wbase += wsms[w];
    int ex = bbase[b] + wbase + (sc - s);  // exclusive prefix for this thread's first elem
#pragma unroll
    for (int k = 0; k < 8; ++k) {
        int idx = base + k;
        if (idx < N) { off[idx] = ex; cur[idx] = ex; }
        ex += v[k];
    }
    if (b == NB - 1 && t == 255) off[N] = ex;  // total E
}

__global__ void k_scatter(const int* src, const int* dst, int* cur, int* csr_src, int E) {
    int e = blockIdx.x * blockDim.x + threadIdx.x;
    if (e >= E) return;
    int d = dst[e];
    int pos = atomicAdd(&cur[d], 1);
    csr_src[pos] = src[e];
}

// Layer 1 (scalar GAT) + hrelu/a2s/a2d production. One 64-lane wave per node.
__global__ void kL1_fused(const float* x, const float* consts, const int* off,
                          const int* csr_src, const float* W1, const float* b1,
                          float* hrelu, float* a2s, float* a2d, int N) {
    int i = blockIdx.x * blockDim.y + threadIdx.y;
    int lane = threadIdx.x;
    if (i >= N) return;
    float cs = consts[0], cd = consts[1];
    float xi = x[i];
    float m = LRELU(xi * (cs + cd));  // self-loop score
    float z = 1.f, wx = xi;           // self-loop weight 1 at m
    int lo = off[i], hi = off[i + 1];
    for (int base = lo; base < hi; base += 64) {
        int j = base + lane;
        float e = -INFINITY, xs = 0.f;
        if (j < hi) {
            int s = csr_src[j];
            xs = x[s];
            e = LRELU(cs * xs + cd * xi);
        }
        float mn = fmaxf(m, wmax(e));
        float sc = __expf(m - mn);
        float w = (j < hi) ? __expf(e - mn) : 0.f;
        z = z * sc + wsum(w);
        wx = wx * sc + wsum(w * xs);
        m = mn;
    }
    float a1 = wx / z;
    float h = fmaxf(a1 * W1[lane] + b1[lane], 0.f);
    hrelu[(size_t)i * 64 + lane] = h;
    float ps = wsum(h * consts[C_VAS + lane]);
    float pd = wsum(h * consts[C_VAD + lane]);
    if (lane == 0) { a2s[i] = ps; a2d[i] = pd; }
}

// Layer 2 GAT agg (vector, online softmax) + fused Wc matmul + final output.
__global__ void kL2_fused(const float* x, const float* consts, const int* off,
                          const int* csr_src, const float* a2s, const float* a2d,
                          const float* hrelu, const float* Wl1, const float* bl1,
                          float* out, int N) {
    int i = blockIdx.x * blockDim.y + threadIdx.y;
    int lane = threadIdx.x;
    if (i >= N) return;
    float adi = a2d[i];
    float m = LRELU(a2s[i] + adi);              // self-loop score
    float z = 1.f;
    float acc = hrelu[(size_t)i * 64 + lane];   // self-loop contribution (w=1)
    int lo = off[i], hi = off[i + 1];
    for (int base = lo; base < hi; base += 64) {
        int j = base + lane;
        float e = -INFINITY;
        int s = 0;
        if (j < hi) {
            s = csr_src[j];
            e = LRELU(a2s[s] + adi);
        }
        float mn = fmaxf(m, wmax(e));
        float sc = __expf(m - mn);
        float we = (j < hi) ? __expf(e - mn) : 0.f;
        z = z * sc + wsum(we);
        acc *= sc;
        int cnt = min(64, hi - base);
        for (int l = 0; l < cnt; ++l) {
            float w = __shfl(we, l);
            int sl = __shfl(s, l);
            acc += w * hrelu[(size_t)sl * 64 + lane];
        }
        m = mn;
    }
    float v = acc / z;
    float acc1 = consts[C_BC + lane], acc2 = consts[C_BC + 64 + lane];
#pragma unroll 8
    for (int j = 0; j < 64; ++j) {
        float vj = __shfl(v, j);
        acc1 += consts[C_WCT + j * 128 + lane] * vj;
        acc2 += consts[C_WCT + j * 128 + 64 + lane] * vj;
    }
    float xi = x[i];
    out[(size_t)i * 128 + lane]      = xi * Wl1[lane]      + bl1[lane]      + fmaxf(acc1, 0.f);
    out[(size_t)i * 128 + 64 + lane] = xi * Wl1[64 + lane] + bl1[64 + lane] + fmaxf(acc2, 0.f);
}

extern "C" void kernel_launch(void* const* d_in, const int* in_sizes, int n_in,
                              void* d_out, int out_size, void* d_ws, size_t ws_size,
                              hipStream_t stream) {
    const float* x   = (const float*)d_in[0];
    const int*   ei  = (const int*)d_in[1];
    const float* W1  = (const float*)d_in[2];
    const float* as1 = (const float*)d_in[3];
    const float* ad1 = (const float*)d_in[4];
    const float* b1  = (const float*)d_in[5];
    const float* W2  = (const float*)d_in[6];
    const float* as2 = (const float*)d_in[7];
    const float* ad2 = (const float*)d_in[8];
    const float* b2  = (const float*)d_in[9];
    const float* Wl1 = (const float*)d_in[10];
    const float* bl1 = (const float*)d_in[11];
    const float* Wl2 = (const float*)d_in[12];
    const float* bl2 = (const float*)d_in[13];

    int N = in_sizes[0];
    int E = in_sizes[1] / 2;
    const int* srcp = ei;
    const int* dstp = ei + E;

    int NB = (N + 2047) / 2048;  // scan blocks (<=256 assumed)

    float* ws = (float*)d_ws;
    float* consts = ws;                         // 8704 floats
    int*   deg    = (int*)(ws + 8704);          // N
    int*   off    = deg + N;                    // N+1
    int*   cur    = off + N + 1;                // N
    int*   csr    = cur + N;                    // E
    int*   bsum   = csr + E;                    // NB
    int*   bbase  = bsum + NB;                  // NB
    float* a2s    = (float*)(bbase + NB);       // N
    float* a2d    = a2s + N;                    // N
    float* hrel   = a2d + N;                    // 64*N

    dim3 b256(256);
    dim3 bw(64, 4);

    k0_precompute<<<65, 128, 0, stream>>>(W1, as1, ad1, W2, as2, ad2, b2, Wl2, bl2, consts);
    kz_zero<<<(N + 255) / 256, b256, 0, stream>>>(deg, N);
    k_deg<<<(E + 255) / 256, b256, 0, stream>>>(dstp, deg, E);
    k_bsum<<<NB, b256, 0, stream>>>(deg, bsum, N);
    k_bscan<<<1, b256, 0, stream>>>(bsum, bbase, NB);
    k_scan2<<<NB, b256, 0, stream>>>(deg, bbase, off, cur, N, NB);
    k_scatter<<<(E + 255) / 256, b256, 0, stream>>>(srcp, dstp, cur, csr, E);
    kL1_fused<<<(N + 3) / 4, bw, 0, stream>>>(x, consts, off, csr, W1, b1, hrel, a2s, a2d, N);
    kL2_fused<<<(N + 3) / 4, bw, 0, stream>>>(x, consts, off, csr, a2s, a2d, hrel, Wl1, bl1,
                                              (float*)d_out, N);
}

// Round 4
// 235.954 us; speedup vs baseline: 1.9416x; 1.0406x over previous
//
#include <hip/hip_runtime.h>
#include <hip/hip_fp16.h>
#include <math.h>

#define LRELU(v) ((v) > 0.f ? (v) : 0.2f * (v))

__device__ __forceinline__ float wsum(float v) {
#pragma unroll
    for (int m = 1; m < 64; m <<= 1) v += __shfl_xor(v, m);
    return v;
}
__device__ __forceinline__ float wmax(float v) {
#pragma unroll
    for (int m = 1; m < 64; m <<= 1) v = fmaxf(v, __shfl_xor(v, m));
    return v;
}
__device__ __forceinline__ int wsumi(int v) {
#pragma unroll
    for (int m = 1; m < 64; m <<= 1) v += __shfl_xor(v, m);
    return v;
}

// consts layout (floats):
// [0]=cs1 [1]=cd1 [2..65]=va_s(64) [66..129]=va_d(64) [130..257]=bc(128)
// [258..8449]=WcT (64 x 128): WcT[k*128+c] = sum_j Wl2[c][j]*W2[j][k]
#define C_VAS 2
#define C_VAD 66
#define C_BC 130
#define C_WCT 258

__global__ void k0_precompute(const float* W1, const float* as1, const float* ad1,
                              const float* W2, const float* as2, const float* ad2,
                              const float* b2, const float* Wl2, const float* bl2,
                              float* consts) {
    int b = blockIdx.x, t = threadIdx.x;  // blockDim = 128
    if (b < 64) {
        float acc = 0.f;
#pragma unroll 8
        for (int j = 0; j < 128; ++j) acc += Wl2[t * 128 + j] * W2[j * 64 + b];
        consts[C_WCT + b * 128 + t] = acc;
    } else {
        if (t < 64) {
            float vs = 0.f, vd = 0.f;
            for (int c = 0; c < 128; ++c) {
                float w = W2[c * 64 + t];
                vs += as2[c] * w;
                vd += ad2[c] * w;
            }
            consts[C_VAS + t] = vs;
            consts[C_VAD + t] = vd;
        }
        float acc = bl2[t];
        for (int j = 0; j < 128; ++j) acc += Wl2[t * 128 + j] * b2[j];
        consts[C_BC + t] = acc;
        if (t < 64) {
            float p = W1[t] * as1[t], q = W1[t] * ad1[t];
#pragma unroll
            for (int m = 1; m < 64; m <<= 1) { p += __shfl_xor(p, m); q += __shfl_xor(q, m); }
            if (t == 0) { consts[0] = p; consts[1] = q; }
        }
    }
}

__global__ void kz_zero(int* deg, int N) {
    int i = blockIdx.x * blockDim.x + threadIdx.x;
    if (i < N) deg[i] = 0;
}

__global__ void k_deg(const int* dst, int* deg, int E) {
    int e = blockIdx.x * blockDim.x + threadIdx.x;
    if (e < E) atomicAdd(&deg[dst[e]], 1);
}

// ---- hierarchical scan: 2048 elems per block ----
__global__ void k_bsum(const int* deg, int* bsum, int N) {
    __shared__ int ws[4];
    int t = threadIdx.x, lane = t & 63, wy = t >> 6;
    int base = blockIdx.x * 2048 + t * 8;
    int s = 0;
#pragma unroll
    for (int k = 0; k < 8; ++k) {
        int idx = base + k;
        if (idx < N) s += deg[idx];
    }
    s = wsumi(s);
    if (lane == 0) ws[wy] = s;
    __syncthreads();
    if (t == 0) bsum[blockIdx.x] = ws[0] + ws[1] + ws[2] + ws[3];
}

__global__ void k_bscan(const int* bsum, int* bbase, int NB) {
    __shared__ int sm[256];
    int t = threadIdx.x;  // 256; assumes NB <= 256
    int v = (t < NB) ? bsum[t] : 0;
    sm[t] = v;
    __syncthreads();
    for (int d = 1; d < 256; d <<= 1) {
        int u = (t >= d) ? sm[t - d] : 0;
        __syncthreads();
        sm[t] += u;
        __syncthreads();
    }
    if (t < NB) bbase[t] = sm[t] - v;  // exclusive
}

__global__ void k_scan2(const int* deg, const int* bbase, int* off, int* cur, int N, int NB) {
    __shared__ int wsms[4];
    int b = blockIdx.x, t = threadIdx.x;  // 256 threads
    int lane = t & 63, wy = t >> 6;
    int base = b * 2048 + t * 8;
    int v[8];
    int s = 0;
#pragma unroll
    for (int k = 0; k < 8; ++k) {
        int idx = base + k;
        v[k] = (idx < N) ? deg[idx] : 0;
        s += v[k];
    }
    int sc = s;  // wave inclusive scan of per-thread sums
#pragma unroll
    for (int d = 1; d < 64; d <<= 1) {
        int u = __shfl_up(sc, d);
        if (lane >= d) sc += u;
    }
    if (lane == 63) wsms[wy] = sc;
    __syncthreads();
    int wbase = 0;
    for (int w = 0; w < wy; ++w) wbase += wsms[w];
    int ex = bbase[b] + wbase + (sc - s);  // exclusive prefix for this thread's first elem
#pragma unroll
    for (int k = 0; k < 8; ++k) {
        int idx = base + k;
        if (idx < N) { off[idx] = ex; cur[idx] = ex; }
        ex += v[k];
    }
    if (b == NB - 1 && t == 255) off[N] = ex;  // total E
}

__global__ void k_scatter(const int* src, const int* dst, int* cur, int* csr_src, int E) {
    int e = blockIdx.x * blockDim.x + threadIdx.x;
    if (e >= E) return;
    int d = dst[e];
    int pos = atomicAdd(&cur[d], 1);
    csr_src[pos] = src[e];
}

// Layer 1 (scalar GAT) + hrelu(fp16)/a2s/a2d production. One 64-lane wave per node.
__global__ void kL1_fused(const float* x, const float* consts, const int* off,
                          const int* csr_src, const float* W1, const float* b1,
                          __half* hrelu, float* a2s, float* a2d, int N) {
    int i = blockIdx.x * blockDim.y + threadIdx.y;
    int lane = threadIdx.x;
    if (i >= N) return;
    float cs = consts[0], cd = consts[1];
    float xi = x[i];
    float m = LRELU(xi * (cs + cd));  // self-loop score
    float z = 1.f, wx = xi;           // self-loop weight 1 at m
    int lo = off[i], hi = off[i + 1];
    for (int base = lo; base < hi; base += 64) {
        int j = base + lane;
        float e = -INFINITY, xs = 0.f;
        if (j < hi) {
            int s = csr_src[j];
            xs = x[s];
            e = LRELU(cs * xs + cd * xi);
        }
        float mn = fmaxf(m, wmax(e));
        float sc = __expf(m - mn);
        float w = (j < hi) ? __expf(e - mn) : 0.f;
        z = z * sc + wsum(w);
        wx = wx * sc + wsum(w * xs);
        m = mn;
    }
    float a1 = wx / z;
    float h = fmaxf(a1 * W1[lane] + b1[lane], 0.f);
    hrelu[(size_t)i * 64 + lane] = __float2half(h);
    float ps = wsum(h * consts[C_VAS + lane]);
    float pd = wsum(h * consts[C_VAD + lane]);
    if (lane == 0) { a2s[i] = ps; a2d[i] = pd; }
}

// Layer 2 GAT agg (vector, online softmax, 4-deep prefetch) + fused Wc matmul + output.
__global__ void kL2_fused(const float* x, const float* consts, const int* off,
                          const int* csr_src, const float* a2s, const float* a2d,
                          const __half* hrelu, const float* Wl1, const float* bl1,
                          float* out, int N) {
    int i = blockIdx.x * blockDim.y + threadIdx.y;
    int lane = threadIdx.x;
    if (i >= N) return;
    float adi = a2d[i];
    float m = LRELU(a2s[i] + adi);              // self-loop score
    float z = 1.f;
    float acc = __half2float(hrelu[(size_t)i * 64 + lane]);  // self-loop (w=1)
    int lo = off[i], hi = off[i + 1];
    for (int base = lo; base < hi; base += 64) {
        int j = base + lane;
        float e = -INFINITY;
        int s = 0;
        if (j < hi) {
            s = csr_src[j];
            e = LRELU(a2s[s] + adi);
        }
        float mn = fmaxf(m, wmax(e));
        float sc = __expf(m - mn);
        float we = (j < hi) ? __expf(e - mn) : 0.f;
        z = z * sc + wsum(we);
        acc *= sc;
        int cnt = min(64, hi - base);
        int l = 0;
        for (; l + 4 <= cnt; l += 4) {
            float w0 = __shfl(we, l),     w1 = __shfl(we, l + 1);
            float w2 = __shfl(we, l + 2), w3 = __shfl(we, l + 3);
            int s0 = __shfl(s, l),     s1 = __shfl(s, l + 1);
            int s2 = __shfl(s, l + 2), s3 = __shfl(s, l + 3);
            float v0 = __half2float(hrelu[(size_t)s0 * 64 + lane]);
            float v1 = __half2float(hrelu[(size_t)s1 * 64 + lane]);
            float v2 = __half2float(hrelu[(size_t)s2 * 64 + lane]);
            float v3 = __half2float(hrelu[(size_t)s3 * 64 + lane]);
            acc += w0 * v0 + w1 * v1 + w2 * v2 + w3 * v3;
        }
        for (; l < cnt; ++l) {
            float w = __shfl(we, l);
            int sl = __shfl(s, l);
            acc += w * __half2float(hrelu[(size_t)sl * 64 + lane]);
        }
        m = mn;
    }
    float v = acc / z;
    float acc1 = consts[C_BC + lane], acc2 = consts[C_BC + 64 + lane];
#pragma unroll 8
    for (int j = 0; j < 64; ++j) {
        float vj = __shfl(v, j);
        acc1 += consts[C_WCT + j * 128 + lane] * vj;
        acc2 += consts[C_WCT + j * 128 + 64 + lane] * vj;
    }
    float xi = x[i];
    out[(size_t)i * 128 + lane]      = xi * Wl1[lane]      + bl1[lane]      + fmaxf(acc1, 0.f);
    out[(size_t)i * 128 + 64 + lane] = xi * Wl1[64 + lane] + bl1[64 + lane] + fmaxf(acc2, 0.f);
}

extern "C" void kernel_launch(void* const* d_in, const int* in_sizes, int n_in,
                              void* d_out, int out_size, void* d_ws, size_t ws_size,
                              hipStream_t stream) {
    const float* x   = (const float*)d_in[0];
    const int*   ei  = (const int*)d_in[1];
    const float* W1  = (const float*)d_in[2];
    const float* as1 = (const float*)d_in[3];
    const float* ad1 = (const float*)d_in[4];
    const float* b1  = (const float*)d_in[5];
    const float* W2  = (const float*)d_in[6];
    const float* as2 = (const float*)d_in[7];
    const float* ad2 = (const float*)d_in[8];
    const float* b2  = (const float*)d_in[9];
    const float* Wl1 = (const float*)d_in[10];
    const float* bl1 = (const float*)d_in[11];
    const float* Wl2 = (const float*)d_in[12];
    const float* bl2 = (const float*)d_in[13];

    int N = in_sizes[0];
    int E = in_sizes[1] / 2;
    const int* srcp = ei;
    const int* dstp = ei + E;

    int NB = (N + 2047) / 2048;  // scan blocks (<=256 assumed)

    float* ws = (float*)d_ws;
    float* consts = ws;                         // 8704 floats
    int*   deg    = (int*)(ws + 8704);          // N
    int*   off    = deg + N;                    // N+1
    int*   cur    = off + N + 1;                // N
    int*   csr    = cur + N;                    // E
    int*   bsum   = csr + E;                    // NB
    int*   bbase  = bsum + NB;                  // NB
    float* a2s    = (float*)(bbase + NB);       // N
    float* a2d    = a2s + N;                    // N
    __half* hrel  = (__half*)(a2d + N);         // 64*N halves

    dim3 b256(256);
    dim3 bw(64, 4);

    k0_precompute<<<65, 128, 0, stream>>>(W1, as1, ad1, W2, as2, ad2, b2, Wl2, bl2, consts);
    kz_zero<<<(N + 255) / 256, b256, 0, stream>>>(deg, N);
    k_deg<<<(E + 255) / 256, b256, 0, stream>>>(dstp, deg, E);
    k_bsum<<<NB, b256, 0, stream>>>(deg, bsum, N);
    k_bscan<<<1, b256, 0, stream>>>(bsum, bbase, NB);
    k_scan2<<<NB, b256, 0, stream>>>(deg, bbase, off, cur, N, NB);
    k_scatter<<<(E + 255) / 256, b256, 0, stream>>>(srcp, dstp, cur, csr, E);
    kL1_fused<<<(N + 3) / 4, bw, 0, stream>>>(x, consts, off, csr, W1, b1, hrel, a2s, a2d, N);
    kL2_fused<<<(N + 3) / 4, bw, 0, stream>>>(x, consts, off, csr, a2s, a2d, hrel, Wl1, bl1,
                                              (float*)d_out, N);
}

// Round 5
// 192.789 us; speedup vs baseline: 2.3763x; 1.2239x over previous
//
#include <hip/hip_runtime.h>
#include <hip/hip_fp16.h>
#include <math.h>

#define LRELU(v) ((v) > 0.f ? (v) : 0.2f * (v))

__device__ __forceinline__ float wsum(float v) {
#pragma unroll
    for (int m = 1; m < 64; m <<= 1) v += __shfl_xor(v, m);
    return v;
}
__device__ __forceinline__ int wsumi(int v) {
#pragma unroll
    for (int m = 1; m < 64; m <<= 1) v += __shfl_xor(v, m);
    return v;
}

// consts layout (floats):
// [0]=cs1 [1]=cd1 [2..65]=va_s(64) [66..129]=va_d(64) [130..257]=bc(128)
// [258..8449]=WcT (64 x 128): WcT[k*128+c] = sum_j Wl2[c][j]*W2[j][k]
#define C_VAS 2
#define C_VAD 66
#define C_BC 130
#define C_WCT 258

__global__ void k0_precompute(const float* W1, const float* as1, const float* ad1,
                              const float* W2, const float* as2, const float* ad2,
                              const float* b2, const float* Wl2, const float* bl2,
                              float* consts) {
    int b = blockIdx.x, t = threadIdx.x;  // blockDim = 128
    if (b < 64) {
        float acc = 0.f;
#pragma unroll 8
        for (int j = 0; j < 128; ++j) acc += Wl2[t * 128 + j] * W2[j * 64 + b];
        consts[C_WCT + b * 128 + t] = acc;
    } else {
        if (t < 64) {
            float vs = 0.f, vd = 0.f;
            for (int c = 0; c < 128; ++c) {
                float w = W2[c * 64 + t];
                vs += as2[c] * w;
                vd += ad2[c] * w;
            }
            consts[C_VAS + t] = vs;
            consts[C_VAD + t] = vd;
        }
        float acc = bl2[t];
        for (int j = 0; j < 128; ++j) acc += Wl2[t * 128 + j] * b2[j];
        consts[C_BC + t] = acc;
        if (t < 64) {
            float p = W1[t] * as1[t], q = W1[t] * ad1[t];
#pragma unroll
            for (int m = 1; m < 64; m <<= 1) { p += __shfl_xor(p, m); q += __shfl_xor(q, m); }
            if (t == 0) { consts[0] = p; consts[1] = q; }
        }
    }
}

__global__ void kz_zero(int* deg, int N) {
    int i = blockIdx.x * blockDim.x + threadIdx.x;
    if (i < N) deg[i] = 0;
}

__global__ void k_deg(const int* dst, int* deg, int E) {
    int e = blockIdx.x * blockDim.x + threadIdx.x;
    if (e < E) atomicAdd(&deg[dst[e]], 1);
}

// ---- hierarchical scan: 2048 elems per block ----
__global__ void k_bsum(const int* deg, int* bsum, int N) {
    __shared__ int ws[4];
    int t = threadIdx.x, lane = t & 63, wy = t >> 6;
    int base = blockIdx.x * 2048 + t * 8;
    int s = 0;
#pragma unroll
    for (int k = 0; k < 8; ++k) {
        int idx = base + k;
        if (idx < N) s += deg[idx];
    }
    s = wsumi(s);
    if (lane == 0) ws[wy] = s;
    __syncthreads();
    if (t == 0) bsum[blockIdx.x] = ws[0] + ws[1] + ws[2] + ws[3];
}

__global__ void k_bscan(const int* bsum, int* bbase, int NB) {
    __shared__ int sm[256];
    int t = threadIdx.x;  // 256; assumes NB <= 256
    int v = (t < NB) ? bsum[t] : 0;
    sm[t] = v;
    __syncthreads();
    for (int d = 1; d < 256; d <<= 1) {
        int u = (t >= d) ? sm[t - d] : 0;
        __syncthreads();
        sm[t] += u;
        __syncthreads();
    }
    if (t < NB) bbase[t] = sm[t] - v;  // exclusive
}

__global__ void k_scan2(const int* deg, const int* bbase, int* off, int* cur, int N, int NB) {
    __shared__ int wsms[4];
    int b = blockIdx.x, t = threadIdx.x;  // 256 threads
    int lane = t & 63, wy = t >> 6;
    int base = b * 2048 + t * 8;
    int v[8];
    int s = 0;
#pragma unroll
    for (int k = 0; k < 8; ++k) {
        int idx = base + k;
        v[k] = (idx < N) ? deg[idx] : 0;
        s += v[k];
    }
    int sc = s;  // wave inclusive scan of per-thread sums
#pragma unroll
    for (int d = 1; d < 64; d <<= 1) {
        int u = __shfl_up(sc, d);
        if (lane >= d) sc += u;
    }
    if (lane == 63) wsms[wy] = sc;
    __syncthreads();
    int wbase = 0;
    for (int w = 0; w < wy; ++w) wbase += wsms[w];
    int ex = bbase[b] + wbase + (sc - s);  // exclusive prefix for this thread's first elem
#pragma unroll
    for (int k = 0; k < 8; ++k) {
        int idx = base + k;
        if (idx < N) { off[idx] = ex; cur[idx] = ex; }
        ex += v[k];
    }
    if (b == NB - 1 && t == 255) off[N] = ex;  // total E
}

__global__ void k_scatter(const int* src, const int* dst, int* cur, int* csr_src, int E) {
    int e = blockIdx.x * blockDim.x + threadIdx.x;
    if (e >= E) return;
    int d = dst[e];
    int pos = atomicAdd(&cur[d], 1);
    csr_src[pos] = src[e];
}

// Layer 1 (scalar GAT, no-max softmax) + hrelu(fp16)/a2s/a2d. One wave per node.
__global__ void kL1_fused(const float* x, const float* consts, const int* off,
                          const int* csr_src, const float* W1, const float* b1,
                          __half* hrelu, float* a2s, float* a2d, int N) {
    int i = blockIdx.x * blockDim.y + threadIdx.y;
    int lane = threadIdx.x;
    if (i >= N) return;
    float cs = consts[0], cd = consts[1];
    float xi = x[i];
    float w0 = __expf(LRELU(xi * (cs + cd)));  // self-loop weight (no max-sub; |e| small)
    float z = w0, wx = w0 * xi;
    int lo = off[i], hi = off[i + 1];
    for (int base = lo; base < hi; base += 64) {
        int j = base + lane;
        float w = 0.f, xs = 0.f;
        if (j < hi) {
            int s = csr_src[j];
            xs = x[s];
            w = __expf(LRELU(cs * xs + cd * xi));
        }
        z += wsum(w);
        wx += wsum(w * xs);
    }
    float a1 = wx / z;
    float h = fmaxf(a1 * W1[lane] + b1[lane], 0.f);
    hrelu[(size_t)i * 64 + lane] = __float2half(h);
    float ps = wsum(h * consts[C_VAS + lane]);
    float pd = wsum(h * consts[C_VAD + lane]);
    if (lane == 0) { a2s[i] = ps; a2d[i] = pd; }
}

// Layer 2 aggregation (no-max softmax, quad-row gather). Writes normalized v (64 floats)
// into the LOW HALF of this node's out row (out[i*128 + 0..63]) — exclusively owned.
__global__ void kL2_agg(const int* off, const int* csr_src, const float* a2s,
                        const float* a2d, const __half* hrelu, float* outv, int N) {
    int i = blockIdx.x * blockDim.y + threadIdx.y;
    int lane = threadIdx.x;
    if (i >= N) return;
    int grp = lane >> 4, c = lane & 15;
    float adi = a2d[i];
    float w0 = __expf(LRELU(a2s[i] + adi));  // self-loop
    float z = w0;
    float a0, a1, a2, a3;
    {
        uint2 r = *(const uint2*)(hrelu + (size_t)i * 64 + 4 * c);
        float2 p0 = __half22float2(*(const __half2*)&r.x);
        float2 p1 = __half22float2(*(const __half2*)&r.y);
        float sw = (grp == 0) ? w0 : 0.f;  // self contribution counted once
        a0 = sw * p0.x; a1 = sw * p0.y; a2 = sw * p1.x; a3 = sw * p1.y;
    }
    int lo = off[i], hi = off[i + 1];
    for (int base = lo; base < hi; base += 64) {
        int j = base + lane;
        bool valid = j < hi;
        int s = valid ? csr_src[j] : 0;
        float w = 0.f;
        if (valid) w = __expf(LRELU(a2s[s] + adi));
        z += wsum(w);
        int cnt = min(64, hi - base);
        for (int g = grp; g < cnt; g += 4) {  // 4 groups x 16 lanes: 4 rows per load instr
            int sg = __shfl(s, g);
            float wg = __shfl(w, g);
            uint2 r = *(const uint2*)(hrelu + (size_t)sg * 64 + 4 * c);
            float2 p0 = __half22float2(*(const __half2*)&r.x);
            float2 p1 = __half22float2(*(const __half2*)&r.y);
            a0 += wg * p0.x; a1 += wg * p0.y; a2 += wg * p1.x; a3 += wg * p1.y;
        }
    }
#pragma unroll
    for (int mk = 16; mk < 64; mk <<= 1) {  // sum the 4 groups
        a0 += __shfl_xor(a0, mk);
        a1 += __shfl_xor(a1, mk);
        a2 += __shfl_xor(a2, mk);
        a3 += __shfl_xor(a3, mk);
    }
    if (grp == 0) {
        float inv = 1.f / z;
        float4 o = make_float4(a0 * inv, a1 * inv, a2 * inv, a3 * inv);
        *(float4*)(outv + (size_t)i * 128 + 4 * c) = o;
    }
}

// Streaming GEMM epilogue: out[i, 0:128] = x2 + relu(WcT^T v_i + bc).
// Reads v from low half of out rows (tile-exclusive), stages in LDS, overwrites row.
__global__ void k_out(const float* x, const float* consts, const float* Wl1,
                      const float* bl1, float* out, int N) {
    __shared__ float sv[64 * 64];
    int lane = threadIdx.x, wy = threadIdx.y;  // (64,4)
    int tile = blockIdx.x * 64;
    int nNodes = min(64, N - tile);
    int t = wy * 64 + lane;  // 0..255
    // stage v rows: node k's v = out[(tile+k)*128 + 0..63]
    int nf4 = nNodes * 16;  // float4s
    for (int f = t; f < nf4; f += 256) {
        int k = f >> 4, j4 = f & 15;
        sv[k * 64 + j4 * 4 + 0] = out[(size_t)(tile + k) * 128 + j4 * 4 + 0];
        sv[k * 64 + j4 * 4 + 1] = out[(size_t)(tile + k) * 128 + j4 * 4 + 1];
        sv[k * 64 + j4 * 4 + 2] = out[(size_t)(tile + k) * 128 + j4 * 4 + 2];
        sv[k * 64 + j4 * 4 + 3] = out[(size_t)(tile + k) * 128 + j4 * 4 + 3];
    }
    __syncthreads();
    int oc = lane + 64 * (wy & 1);
    float Wreg[64];
#pragma unroll
    for (int j = 0; j < 64; ++j) Wreg[j] = consts[C_WCT + j * 128 + oc];
    float bc = consts[C_BC + oc];
    float wl = Wl1[oc], bl = bl1[oc];
    for (int k = (wy >> 1); k < nNodes; k += 2) {
        int node = tile + k;
        const float4* svp = (const float4*)(sv + k * 64);
        float acc = bc;
#pragma unroll
        for (int j4 = 0; j4 < 16; ++j4) {
            float4 vv = svp[j4];
            acc += Wreg[4 * j4 + 0] * vv.x;
            acc += Wreg[4 * j4 + 1] * vv.y;
            acc += Wreg[4 * j4 + 2] * vv.z;
            acc += Wreg[4 * j4 + 3] * vv.w;
        }
        out[(size_t)node * 128 + oc] = x[node] * wl + bl + fmaxf(acc, 0.f);
    }
}

extern "C" void kernel_launch(void* const* d_in, const int* in_sizes, int n_in,
                              void* d_out, int out_size, void* d_ws, size_t ws_size,
                              hipStream_t stream) {
    const float* x   = (const float*)d_in[0];
    const int*   ei  = (const int*)d_in[1];
    const float* W1  = (const float*)d_in[2];
    const float* as1 = (const float*)d_in[3];
    const float* ad1 = (const float*)d_in[4];
    const float* b1  = (const float*)d_in[5];
    const float* W2  = (const float*)d_in[6];
    const float* as2 = (const float*)d_in[7];
    const float* ad2 = (const float*)d_in[8];
    const float* b2  = (const float*)d_in[9];
    const float* Wl1 = (const float*)d_in[10];
    const float* bl1 = (const float*)d_in[11];
    const float* Wl2 = (const float*)d_in[12];
    const float* bl2 = (const float*)d_in[13];

    int N = in_sizes[0];
    int E = in_sizes[1] / 2;
    const int* srcp = ei;
    const int* dstp = ei + E;

    int NB = (N + 2047) / 2048;  // scan blocks (<=256 assumed)

    float* ws = (float*)d_ws;
    float* consts = ws;                         // 8704 floats
    int*   deg    = (int*)(ws + 8704);          // N
    int*   off    = deg + N;                    // N+1
    int*   cur    = off + N + 1;                // N
    int*   csr    = cur + N;                    // E
    int*   bsum   = csr + E;                    // NB
    int*   bbase  = bsum + NB;                  // NB
    float* a2s    = (float*)(bbase + NB);       // N
    float* a2d    = a2s + N;                    // N
    __half* hrel  = (__half*)(a2d + N);         // 64*N halves

    float* outp = (float*)d_out;

    dim3 b256(256);
    dim3 bw(64, 4);

    k0_precompute<<<65, 128, 0, stream>>>(W1, as1, ad1, W2, as2, ad2, b2, Wl2, bl2, consts);
    kz_zero<<<(N + 255) / 256, b256, 0, stream>>>(deg, N);
    k_deg<<<(E + 255) / 256, b256, 0, stream>>>(dstp, deg, E);
    k_bsum<<<NB, b256, 0, stream>>>(deg, bsum, N);
    k_bscan<<<1, b256, 0, stream>>>(bsum, bbase, NB);
    k_scan2<<<NB, b256, 0, stream>>>(deg, bbase, off, cur, N, NB);
    k_scatter<<<(E + 255) / 256, b256, 0, stream>>>(srcp, dstp, cur, csr, E);
    kL1_fused<<<(N + 3) / 4, bw, 0, stream>>>(x, consts, off, csr, W1, b1, hrel, a2s, a2d, N);
    kL2_agg<<<(N + 3) / 4, bw, 0, stream>>>(off, csr, a2s, a2d, hrel, outp, N);
    k_out<<<(N + 63) / 64, bw, 0, stream>>>(x, consts, Wl1, bl1, outp, N);
}

// Round 6
// 179.967 us; speedup vs baseline: 2.5456x; 1.0713x over previous
//
#include <hip/hip_runtime.h>
#include <hip/hip_fp16.h>
#include <math.h>

#define LRELU(v) ((v) > 0.f ? (v) : 0.2f * (v))

using short8 = __attribute__((ext_vector_type(8))) short;
using f32x4  = __attribute__((ext_vector_type(4))) float;

__device__ __forceinline__ float wsum(float v) {
#pragma unroll
    for (int m = 1; m < 64; m <<= 1) v += __shfl_xor(v, m);
    return v;
}
__device__ __forceinline__ int wsumi(int v) {
#pragma unroll
    for (int m = 1; m < 64; m <<= 1) v += __shfl_xor(v, m);
    return v;
}
__device__ __forceinline__ unsigned short f2bf(float f) {
    unsigned int u = __float_as_uint(f);
    u += 0x7fffu + ((u >> 16) & 1u);
    return (unsigned short)(u >> 16);
}

// consts layout (floats):
// [0]=cs1 [1]=cd1 [2..65]=va_s(64) [66..129]=va_d(64) [130..257]=bc(128)
// [258..8449]=WcT (64 x 128): WcT[k*128+c] = sum_j Wl2[c][j]*W2[j][k]
#define C_VAS 2
#define C_VAD 66
#define C_BC 130
#define C_WCT 258

__global__ void k0_precompute(const float* W1, const float* as1, const float* ad1,
                              const float* W2, const float* as2, const float* ad2,
                              const float* b2, const float* Wl2, const float* bl2,
                              float* consts, unsigned short* Whc) {
    int b = blockIdx.x, t = threadIdx.x;  // blockDim = 128
    if (b < 64) {
        float acc = 0.f;
#pragma unroll 8
        for (int j = 0; j < 128; ++j) acc += Wl2[t * 128 + j] * W2[j * 64 + b];
        consts[C_WCT + b * 128 + t] = acc;
        Whc[t * 64 + b] = f2bf(acc);  // B^T layout: Whc[col][k]
    } else {
        if (t < 64) {
            float vs = 0.f, vd = 0.f;
            for (int c = 0; c < 128; ++c) {
                float w = W2[c * 64 + t];
                vs += as2[c] * w;
                vd += ad2[c] * w;
            }
            consts[C_VAS + t] = vs;
            consts[C_VAD + t] = vd;
        }
        float acc = bl2[t];
        for (int j = 0; j < 128; ++j) acc += Wl2[t * 128 + j] * b2[j];
        consts[C_BC + t] = acc;
        if (t < 64) {
            float p = W1[t] * as1[t], q = W1[t] * ad1[t];
#pragma unroll
            for (int m = 1; m < 64; m <<= 1) { p += __shfl_xor(p, m); q += __shfl_xor(q, m); }
            if (t == 0) { consts[0] = p; consts[1] = q; }
        }
    }
}

__global__ void k_deg(const int* dst, int* deg, int E) {
    int e = blockIdx.x * blockDim.x + threadIdx.x;
    if (e < E) atomicAdd(&deg[dst[e]], 1);
}

// ---- hierarchical scan: 2048 elems per block ----
__global__ void k_bsum(const int* deg, int* bsum, int N) {
    __shared__ int ws[4];
    int t = threadIdx.x, lane = t & 63, wy = t >> 6;
    int base = blockIdx.x * 2048 + t * 8;
    int s = 0;
#pragma unroll
    for (int k = 0; k < 8; ++k) {
        int idx = base + k;
        if (idx < N) s += deg[idx];
    }
    s = wsumi(s);
    if (lane == 0) ws[wy] = s;
    __syncthreads();
    if (t == 0) bsum[blockIdx.x] = ws[0] + ws[1] + ws[2] + ws[3];
}

__global__ void k_bscan(const int* bsum, int* bbase, int NB) {
    __shared__ int sm[256];
    int t = threadIdx.x;  // 256; assumes NB <= 256
    int v = (t < NB) ? bsum[t] : 0;
    sm[t] = v;
    __syncthreads();
    for (int d = 1; d < 256; d <<= 1) {
        int u = (t >= d) ? sm[t - d] : 0;
        __syncthreads();
        sm[t] += u;
        __syncthreads();
    }
    if (t < NB) bbase[t] = sm[t] - v;  // exclusive
}

__global__ void k_scan2(const int* deg, const int* bbase, int* off, int* cur, int N, int NB) {
    __shared__ int wsms[4];
    int b = blockIdx.x, t = threadIdx.x;  // 256 threads
    int lane = t & 63, wy = t >> 6;
    int base = b * 2048 + t * 8;
    int v[8];
    int s = 0;
#pragma unroll
    for (int k = 0; k < 8; ++k) {
        int idx = base + k;
        v[k] = (idx < N) ? deg[idx] : 0;
        s += v[k];
    }
    int sc = s;  // wave inclusive scan of per-thread sums
#pragma unroll
    for (int d = 1; d < 64; d <<= 1) {
        int u = __shfl_up(sc, d);
        if (lane >= d) sc += u;
    }
    if (lane == 63) wsms[wy] = sc;
    __syncthreads();
    int wbase = 0;
    for (int w = 0; w < wy; ++w) wbase += wsms[w];
    int ex = bbase[b] + wbase + (sc - s);  // exclusive prefix for this thread's first elem
#pragma unroll
    for (int k = 0; k < 8; ++k) {
        int idx = base + k;
        if (idx < N) { off[idx] = ex; cur[idx] = ex; }
        ex += v[k];
    }
    if (b == NB - 1 && t == 255) off[N] = ex;  // total E
}

__global__ void k_scatter(const int* src, const int* dst, int* cur, int* csr_src, int E) {
    int e = blockIdx.x * blockDim.x + threadIdx.x;
    if (e >= E) return;
    int d = dst[e];
    int pos = atomicAdd(&cur[d], 1);
    csr_src[pos] = src[e];
}

// Layer 1 (scalar GAT, no-max softmax) + hrelu(fp16)/a2s/a2d. One wave per node.
__global__ void kL1_fused(const float* x, const float* consts, const int* off,
                          const int* csr_src, const float* W1, const float* b1,
                          __half* hrelu, float* a2s, float* a2d, int N) {
    int i = blockIdx.x * blockDim.y + threadIdx.y;
    int lane = threadIdx.x;
    if (i >= N) return;
    float cs = consts[0], cd = consts[1];
    float xi = x[i];
    float w0 = __expf(LRELU(xi * (cs + cd)));  // self-loop weight (no max-sub; |e| small)
    float z = w0, wx = w0 * xi;
    int lo = off[i], hi = off[i + 1];
    for (int base = lo; base < hi; base += 64) {
        int j = base + lane;
        float w = 0.f, xs = 0.f;
        if (j < hi) {
            int s = csr_src[j];
            xs = x[s];
            w = __expf(LRELU(cs * xs + cd * xi));
        }
        z += wsum(w);
        wx += wsum(w * xs);
    }
    float a1 = wx / z;
    float h = fmaxf(a1 * W1[lane] + b1[lane], 0.f);
    hrelu[(size_t)i * 64 + lane] = __float2half(h);
    float ps = wsum(h * consts[C_VAS + lane]);
    float pd = wsum(h * consts[C_VAD + lane]);
    if (lane == 0) { a2s[i] = ps; a2d[i] = pd; }
}

// Layer 2 aggregation (no-max softmax, quad-row gather). Writes normalized v as bf16.
__global__ void kL2_agg(const int* off, const int* csr_src, const float* a2s,
                        const float* a2d, const __half* hrelu, unsigned short* vh, int N) {
    int i = blockIdx.x * blockDim.y + threadIdx.y;
    int lane = threadIdx.x;
    if (i >= N) return;
    int grp = lane >> 4, c = lane & 15;
    float adi = a2d[i];
    float w0 = __expf(LRELU(a2s[i] + adi));  // self-loop
    float z = w0;
    float a0, a1, a2, a3;
    {
        uint2 r = *(const uint2*)(hrelu + (size_t)i * 64 + 4 * c);
        float2 p0 = __half22float2(*(const __half2*)&r.x);
        float2 p1 = __half22float2(*(const __half2*)&r.y);
        float sw = (grp == 0) ? w0 : 0.f;  // self contribution counted once
        a0 = sw * p0.x; a1 = sw * p0.y; a2 = sw * p1.x; a3 = sw * p1.y;
    }
    int lo = off[i], hi = off[i + 1];
    for (int base = lo; base < hi; base += 64) {
        int j = base + lane;
        bool valid = j < hi;
        int s = valid ? csr_src[j] : 0;
        float w = 0.f;
        if (valid) w = __expf(LRELU(a2s[s] + adi));
        z += wsum(w);
        int cnt = min(64, hi - base);
        for (int g = grp; g < cnt; g += 4) {  // 4 groups x 16 lanes: 4 rows per load instr
            int sg = __shfl(s, g);
            float wg = __shfl(w, g);
            uint2 r = *(const uint2*)(hrelu + (size_t)sg * 64 + 4 * c);
            float2 p0 = __half22float2(*(const __half2*)&r.x);
            float2 p1 = __half22float2(*(const __half2*)&r.y);
            a0 += wg * p0.x; a1 += wg * p0.y; a2 += wg * p1.x; a3 += wg * p1.y;
        }
    }
#pragma unroll
    for (int mk = 16; mk < 64; mk <<= 1) {  // sum the 4 groups
        a0 += __shfl_xor(a0, mk);
        a1 += __shfl_xor(a1, mk);
        a2 += __shfl_xor(a2, mk);
        a3 += __shfl_xor(a3, mk);
    }
    if (grp == 0) {
        float inv = 1.f / z;
        uint2 o;
        o.x = (unsigned int)f2bf(a0 * inv) | ((unsigned int)f2bf(a1 * inv) << 16);
        o.y = (unsigned int)f2bf(a2 * inv) | ((unsigned int)f2bf(a3 * inv) << 16);
        *(uint2*)(vh + (size_t)i * 64 + 4 * c) = o;
    }
}

// MFMA epilogue GEMM: out[i,0:128] = x*Wl1 + bl1 + relu(v_i @ Wc + bc).
// Per wave: 16 nodes x 128 cols via 8 coltiles x 2 mfma_f32_16x16x32_bf16.
__global__ void k_out(const float* x, const float* consts, const unsigned short* Whc,
                      const unsigned short* vh, const float* Wl1, const float* bl1,
                      float* out, int N) {
    int lane = threadIdx.x;            // 64
    int tile = blockIdx.x * 64 + threadIdx.y * 16;
    if (tile >= N) return;
    int r = lane & 15, kg = lane >> 4;
    int arow = tile + r;
    if (arow >= N) arow = N - 1;  // pad-safe (unused rows not stored)
    const unsigned short* ap = vh + (size_t)arow * 64 + kg * 8;
    short8 A0 = *(const short8*)ap;
    short8 A1 = *(const short8*)(ap + 32);

    f32x4 acc[8];
#pragma unroll
    for (int ct = 0; ct < 8; ++ct) {
        const unsigned short* bp = Whc + (ct * 16 + r) * 64 + kg * 8;
        short8 B0 = *(const short8*)bp;
        short8 B1 = *(const short8*)(bp + 32);
        f32x4 c = {0.f, 0.f, 0.f, 0.f};
        c = __builtin_amdgcn_mfma_f32_16x16x32_bf16(A0, B0, c, 0, 0, 0);
        c = __builtin_amdgcn_mfma_f32_16x16x32_bf16(A1, B1, c, 0, 0, 0);
        acc[ct] = c;
    }
    float xq[4];
#pragma unroll
    for (int q = 0; q < 4; ++q) {
        int node = tile + kg * 4 + q;
        xq[q] = (node < N) ? x[node] : 0.f;
    }
#pragma unroll
    for (int ct = 0; ct < 8; ++ct) {
        int col = ct * 16 + r;
        float wl = Wl1[col], bl = bl1[col], bc = consts[C_BC + col];
#pragma unroll
        for (int q = 0; q < 4; ++q) {
            int node = tile + kg * 4 + q;
            if (node < N)
                out[(size_t)node * 128 + col] = xq[q] * wl + bl + fmaxf(acc[ct][q] + bc, 0.f);
        }
    }
}

extern "C" void kernel_launch(void* const* d_in, const int* in_sizes, int n_in,
                              void* d_out, int out_size, void* d_ws, size_t ws_size,
                              hipStream_t stream) {
    const float* x   = (const float*)d_in[0];
    const int*   ei  = (const int*)d_in[1];
    const float* W1  = (const float*)d_in[2];
    const float* as1 = (const float*)d_in[3];
    const float* ad1 = (const float*)d_in[4];
    const float* b1  = (const float*)d_in[5];
    const float* W2  = (const float*)d_in[6];
    const float* as2 = (const float*)d_in[7];
    const float* ad2 = (const float*)d_in[8];
    const float* b2  = (const float*)d_in[9];
    const float* Wl1 = (const float*)d_in[10];
    const float* bl1 = (const float*)d_in[11];
    const float* Wl2 = (const float*)d_in[12];
    const float* bl2 = (const float*)d_in[13];

    int N = in_sizes[0];
    int E = in_sizes[1] / 2;
    const int* srcp = ei;
    const int* dstp = ei + E;

    int NB = (N + 2047) / 2048;  // scan blocks (<=256 assumed)

    float* ws = (float*)d_ws;
    float* consts = ws;                         // 8704 floats
    int*   deg    = (int*)(ws + 8704);          // N
    int*   off    = deg + N;                    // N+1
    int*   cur    = off + N + 1;                // N
    int*   csr    = cur + N;                    // E
    int*   bsum   = csr + E;                    // NB
    int*   bbase  = bsum + NB;                  // NB
    float* a2s    = (float*)(bbase + NB);       // N
    float* a2d    = a2s + N;                    // N
    __half* hrel  = (__half*)(a2d + N);         // 64*N halves
    unsigned short* vh  = (unsigned short*)(hrel + (size_t)64 * N);  // 64*N bf16
    unsigned short* Whc = vh + (size_t)64 * N;  // 128*64 bf16

    float* outp = (float*)d_out;

    dim3 b256(256);
    dim3 bw(64, 4);

    k0_precompute<<<65, 128, 0, stream>>>(W1, as1, ad1, W2, as2, ad2, b2, Wl2, bl2,
                                          consts, Whc);
    hipMemsetAsync(deg, 0, (size_t)N * sizeof(int), stream);
    k_deg<<<(E + 255) / 256, b256, 0, stream>>>(dstp, deg, E);
    k_bsum<<<NB, b256, 0, stream>>>(deg, bsum, N);
    k_bscan<<<1, b256, 0, stream>>>(bsum, bbase, NB);
    k_scan2<<<NB, b256, 0, stream>>>(deg, bbase, off, cur, N, NB);
    k_scatter<<<(E + 255) / 256, b256, 0, stream>>>(srcp, dstp, cur, csr, E);
    kL1_fused<<<(N + 3) / 4, bw, 0, stream>>>(x, consts, off, csr, W1, b1, hrel, a2s, a2d, N);
    kL2_agg<<<(N + 3) / 4, bw, 0, stream>>>(off, csr, a2s, a2d, hrel, vh, N);
    k_out<<<(N + 63) / 64, bw, 0, stream>>>(x, consts, Whc, vh, Wl1, bl1, outp, N);
}

// Round 7
// 178.843 us; speedup vs baseline: 2.5616x; 1.0063x over previous
//
#include <hip/hip_runtime.h>
#include <hip/hip_fp16.h>
#include <math.h>

#define LRELU(v) ((v) > 0.f ? (v) : 0.2f * (v))

using short8 = __attribute__((ext_vector_type(8))) short;
using f32x4  = __attribute__((ext_vector_type(4))) float;

__device__ __forceinline__ float wsum(float v) {
#pragma unroll
    for (int m = 1; m < 64; m <<= 1) v += __shfl_xor(v, m);
    return v;
}
__device__ __forceinline__ int wsumi(int v) {
#pragma unroll
    for (int m = 1; m < 64; m <<= 1) v += __shfl_xor(v, m);
    return v;
}
__device__ __forceinline__ unsigned short f2bf(float f) {
    unsigned int u = __float_as_uint(f);
    u += 0x7fffu + ((u >> 16) & 1u);
    return (unsigned short)(u >> 16);
}

// consts layout (floats):
// [0]=cs1 [1]=cd1 [2..65]=va_s(64) [66..129]=va_d(64) [130..257]=bc(128)
// [258..8449]=WcT (64 x 128): WcT[k*128+c] = sum_j Wl2[c][j]*W2[j][k]
#define C_VAS 2
#define C_VAD 66
#define C_BC 130
#define C_WCT 258

__global__ void k0_precompute(const float* W1, const float* as1, const float* ad1,
                              const float* W2, const float* as2, const float* ad2,
                              const float* b2, const float* Wl2, const float* bl2,
                              float* consts, unsigned short* Whc) {
    int b = blockIdx.x, t = threadIdx.x;  // blockDim = 128
    if (b < 64) {
        float acc = 0.f;
#pragma unroll 8
        for (int j = 0; j < 128; ++j) acc += Wl2[t * 128 + j] * W2[j * 64 + b];
        consts[C_WCT + b * 128 + t] = acc;
        Whc[t * 64 + b] = f2bf(acc);  // B^T layout: Whc[col][k]
    } else {
        if (t < 64) {
            float vs = 0.f, vd = 0.f;
            for (int c = 0; c < 128; ++c) {
                float w = W2[c * 64 + t];
                vs += as2[c] * w;
                vd += ad2[c] * w;
            }
            consts[C_VAS + t] = vs;
            consts[C_VAD + t] = vd;
        }
        float acc = bl2[t];
        for (int j = 0; j < 128; ++j) acc += Wl2[t * 128 + j] * b2[j];
        consts[C_BC + t] = acc;
        if (t < 64) {
            float p = W1[t] * as1[t], q = W1[t] * ad1[t];
#pragma unroll
            for (int m = 1; m < 64; m <<= 1) { p += __shfl_xor(p, m); q += __shfl_xor(q, m); }
            if (t == 0) { consts[0] = p; consts[1] = q; }
        }
    }
}

__global__ void kz_zero(int* deg, int N) {
    int i = blockIdx.x * blockDim.x + threadIdx.x;
    if (i < N) deg[i] = 0;
}

__global__ void k_deg(const int* dst, int* deg, int E) {
    int e = blockIdx.x * blockDim.x + threadIdx.x;
    if (e < E) atomicAdd(&deg[dst[e]], 1);
}

// ---- hierarchical scan: 2048 elems per block ----
__global__ void k_bsum(const int* deg, int* bsum, int N) {
    __shared__ int ws[4];
    int t = threadIdx.x, lane = t & 63, wy = t >> 6;
    int base = blockIdx.x * 2048 + t * 8;
    int s = 0;
#pragma unroll
    for (int k = 0; k < 8; ++k) {
        int idx = base + k;
        if (idx < N) s += deg[idx];
    }
    s = wsumi(s);
    if (lane == 0) ws[wy] = s;
    __syncthreads();
    if (t == 0) bsum[blockIdx.x] = ws[0] + ws[1] + ws[2] + ws[3];
}

__global__ void k_bscan(const int* bsum, int* bbase, int NB) {
    __shared__ int sm[256];
    int t = threadIdx.x;  // 256; assumes NB <= 256
    int v = (t < NB) ? bsum[t] : 0;
    sm[t] = v;
    __syncthreads();
    for (int d = 1; d < 256; d <<= 1) {
        int u = (t >= d) ? sm[t - d] : 0;
        __syncthreads();
        sm[t] += u;
        __syncthreads();
    }
    if (t < NB) bbase[t] = sm[t] - v;  // exclusive
}

__global__ void k_scan2(const int* deg, const int* bbase, int* off, int* cur, int N, int NB) {
    __shared__ int wsms[4];
    int b = blockIdx.x, t = threadIdx.x;  // 256 threads
    int lane = t & 63, wy = t >> 6;
    int base = b * 2048 + t * 8;
    int v[8];
    int s = 0;
#pragma unroll
    for (int k = 0; k < 8; ++k) {
        int idx = base + k;
        v[k] = (idx < N) ? deg[idx] : 0;
        s += v[k];
    }
    int sc = s;  // wave inclusive scan of per-thread sums
#pragma unroll
    for (int d = 1; d < 64; d <<= 1) {
        int u = __shfl_up(sc, d);
        if (lane >= d) sc += u;
    }
    if (lane == 63) wsms[wy] = sc;
    __syncthreads();
    int wbase = 0;
    for (int w = 0; w < wy; ++w) wbase += wsms[w];
    int ex = bbase[b] + wbase + (sc - s);  // exclusive prefix for this thread's first elem
#pragma unroll
    for (int k = 0; k < 8; ++k) {
        int idx = base + k;
        if (idx < N) { off[idx] = ex; cur[idx] = ex; }
        ex += v[k];
    }
    if (b == NB - 1 && t == 255) off[N] = ex;  // total E
}

__global__ void k_scatter(const int* src, const int* dst, int* cur, int* csr_src, int E) {
    int e = blockIdx.x * blockDim.x + threadIdx.x;
    if (e >= E) return;
    int d = dst[e];
    int pos = atomicAdd(&cur[d], 1);
    csr_src[pos] = src[e];
}

// Layer 1 (scalar GAT, no-max softmax) + hrelu(fp16)/a2s/a2d. One wave per node.
__global__ void kL1_fused(const float* x, const float* consts, const int* off,
                          const int* csr_src, const float* W1, const float* b1,
                          __half* hrelu, float* a2s, float* a2d, int N) {
    int i = blockIdx.x * blockDim.y + threadIdx.y;
    int lane = threadIdx.x;
    if (i >= N) return;
    float cs = consts[0], cd = consts[1];
    float xi = x[i];
    float w0 = __expf(LRELU(xi * (cs + cd)));  // self-loop weight (no max-sub; |e| small)
    float z = w0, wx = w0 * xi;
    int lo = off[i], hi = off[i + 1];
    for (int base = lo; base < hi; base += 64) {
        int j = base + lane;
        float w = 0.f, xs = 0.f;
        if (j < hi) {
            int s = csr_src[j];
            xs = x[s];
            w = __expf(LRELU(cs * xs + cd * xi));
        }
        z += wsum(w);
        wx += wsum(w * xs);
    }
    float a1 = wx / z;
    float h = fmaxf(a1 * W1[lane] + b1[lane], 0.f);
    hrelu[(size_t)i * 64 + lane] = __float2half(h);
    float ps = wsum(h * consts[C_VAS + lane]);
    float pd = wsum(h * consts[C_VAD + lane]);
    if (lane == 0) { a2s[i] = ps; a2d[i] = pd; }
}

// Layer 2 aggregation (no-max softmax, quad-row gather). Writes normalized v as bf16.
__global__ void kL2_agg(const int* off, const int* csr_src, const float* a2s,
                        const float* a2d, const __half* hrelu, unsigned short* vh, int N) {
    int i = blockIdx.x * blockDim.y + threadIdx.y;
    int lane = threadIdx.x;
    if (i >= N) return;
    int grp = lane >> 4, c = lane & 15;
    float adi = a2d[i];
    float w0 = __expf(LRELU(a2s[i] + adi));  // self-loop
    float z = w0;
    float a0, a1, a2, a3;
    {
        uint2 r = *(const uint2*)(hrelu + (size_t)i * 64 + 4 * c);
        float2 p0 = __half22float2(*(const __half2*)&r.x);
        float2 p1 = __half22float2(*(const __half2*)&r.y);
        float sw = (grp == 0) ? w0 : 0.f;  // self contribution counted once
        a0 = sw * p0.x; a1 = sw * p0.y; a2 = sw * p1.x; a3 = sw * p1.y;
    }
    int lo = off[i], hi = off[i + 1];
    for (int base = lo; base < hi; base += 64) {
        int j = base + lane;
        bool valid = j < hi;
        int s = valid ? csr_src[j] : 0;
        float w = 0.f;
        if (valid) w = __expf(LRELU(a2s[s] + adi));
        z += wsum(w);
        int cnt = min(64, hi - base);
        for (int g = grp; g < cnt; g += 4) {  // 4 groups x 16 lanes: 4 rows per load instr
            int sg = __shfl(s, g);
            float wg = __shfl(w, g);
            uint2 r = *(const uint2*)(hrelu + (size_t)sg * 64 + 4 * c);
            float2 p0 = __half22float2(*(const __half2*)&r.x);
            float2 p1 = __half22float2(*(const __half2*)&r.y);
            a0 += wg * p0.x; a1 += wg * p0.y; a2 += wg * p1.x; a3 += wg * p1.y;
        }
    }
#pragma unroll
    for (int mk = 16; mk < 64; mk <<= 1) {  // sum the 4 groups
        a0 += __shfl_xor(a0, mk);
        a1 += __shfl_xor(a1, mk);
        a2 += __shfl_xor(a2, mk);
        a3 += __shfl_xor(a3, mk);
    }
    if (grp == 0) {
        float inv = 1.f / z;
        uint2 o;
        o.x = (unsigned int)f2bf(a0 * inv) | ((unsigned int)f2bf(a1 * inv) << 16);
        o.y = (unsigned int)f2bf(a2 * inv) | ((unsigned int)f2bf(a3 * inv) << 16);
        *(uint2*)(vh + (size_t)i * 64 + 4 * c) = o;
    }
}

// MFMA epilogue GEMM: out[i,0:128] = x*Wl1 + bl1 + relu(v_i @ Wc + bc).
// Per wave: 16 nodes x 128 cols via 8 coltiles x 2 mfma_f32_16x16x32_bf16.
__global__ void k_out(const float* x, const float* consts, const unsigned short* Whc,
                      const unsigned short* vh, const float* Wl1, const float* bl1,
                      float* out, int N) {
    int lane = threadIdx.x;            // 64
    int tile = blockIdx.x * 64 + threadIdx.y * 16;
    if (tile >= N) return;
    int r = lane & 15, kg = lane >> 4;
    int arow = tile + r;
    if (arow >= N) arow = N - 1;  // pad-safe (unused rows not stored)
    const unsigned short* ap = vh + (size_t)arow * 64 + kg * 8;
    short8 A0 = *(const short8*)ap;
    short8 A1 = *(const short8*)(ap + 32);

    f32x4 acc[8];
#pragma unroll
    for (int ct = 0; ct < 8; ++ct) {
        const unsigned short* bp = Whc + (ct * 16 + r) * 64 + kg * 8;
        short8 B0 = *(const short8*)bp;
        short8 B1 = *(const short8*)(bp + 32);
        f32x4 c = {0.f, 0.f, 0.f, 0.f};
        c = __builtin_amdgcn_mfma_f32_16x16x32_bf16(A0, B0, c, 0, 0, 0);
        c = __builtin_amdgcn_mfma_f32_16x16x32_bf16(A1, B1, c, 0, 0, 0);
        acc[ct] = c;
    }
    float xq[4];
#pragma unroll
    for (int q = 0; q < 4; ++q) {
        int node = tile + kg * 4 + q;
        xq[q] = (node < N) ? x[node] : 0.f;
    }
#pragma unroll
    for (int ct = 0; ct < 8; ++ct) {
        int col = ct * 16 + r;
        float wl = Wl1[col], bl = bl1[col], bc = consts[C_BC + col];
#pragma unroll
        for (int q = 0; q < 4; ++q) {
            int node = tile + kg * 4 + q;
            if (node < N)
                out[(size_t)node * 128 + col] = xq[q] * wl + bl + fmaxf(acc[ct][q] + bc, 0.f);
        }
    }
}

extern "C" void kernel_launch(void* const* d_in, const int* in_sizes, int n_in,
                              void* d_out, int out_size, void* d_ws, size_t ws_size,
                              hipStream_t stream) {
    const float* x   = (const float*)d_in[0];
    const int*   ei  = (const int*)d_in[1];
    const float* W1  = (const float*)d_in[2];
    const float* as1 = (const float*)d_in[3];
    const float* ad1 = (const float*)d_in[4];
    const float* b1  = (const float*)d_in[5];
    const float* W2  = (const float*)d_in[6];
    const float* as2 = (const float*)d_in[7];
    const float* ad2 = (const float*)d_in[8];
    const float* b2  = (const float*)d_in[9];
    const float* Wl1 = (const float*)d_in[10];
    const float* bl1 = (const float*)d_in[11];
    const float* Wl2 = (const float*)d_in[12];
    const float* bl2 = (const float*)d_in[13];

    int N = in_sizes[0];
    int E = in_sizes[1] / 2;
    const int* srcp = ei;
    const int* dstp = ei + E;

    int NB = (N + 2047) / 2048;  // scan blocks (<=256 assumed)

    float* ws = (float*)d_ws;
    float* consts = ws;                         // 8704 floats
    int*   deg    = (int*)(ws + 8704);          // N
    int*   off    = deg + N;                    // N+1
    int*   cur    = off + N + 1;                // N
    int*   csr    = cur + N;                    // E
    int*   bsum   = csr + E;                    // NB
    int*   bbase  = bsum + NB;                  // NB
    float* a2s    = (float*)(bbase + NB);       // N
    float* a2d    = a2s + N;                    // N
    __half* hrel  = (__half*)(a2d + N);         // 64*N halves
    unsigned short* vh  = (unsigned short*)(hrel + (size_t)64 * N);  // 64*N bf16
    unsigned short* Whc = vh + (size_t)64 * N;  // 128*64 bf16

    float* outp = (float*)d_out;

    dim3 b256(256);
    dim3 bw(64, 4);

    k0_precompute<<<65, 128, 0, stream>>>(W1, as1, ad1, W2, as2, ad2, b2, Wl2, bl2,
                                          consts, Whc);
    kz_zero<<<(N + 255) / 256, b256, 0, stream>>>(deg, N);
    k_deg<<<(E + 255) / 256, b256, 0, stream>>>(dstp, deg, E);
    k_bsum<<<NB, b256, 0, stream>>>(deg, bsum, N);
    k_bscan<<<1, b256, 0, stream>>>(bsum, bbase, NB);
    k_scan2<<<NB, b256, 0, stream>>>(deg, bbase, off, cur, N, NB);
    k_scatter<<<(E + 255) / 256, b256, 0, stream>>>(srcp, dstp, cur, csr, E);
    kL1_fused<<<(N + 3) / 4, bw, 0, stream>>>(x, consts, off, csr, W1, b1, hrel, a2s, a2d, N);
    kL2_agg<<<(N + 3) / 4, bw, 0, stream>>>(off, csr, a2s, a2d, hrel, vh, N);
    k_out<<<(N + 63) / 64, bw, 0, stream>>>(x, consts, Whc, vh, Wl1, bl1, outp, N);
}